// Round 13
// baseline (553.959 us; speedup 1.0000x reference)
//
#include <hip/hip_runtime.h>
#include <hip/hip_bf16.h>
#include <hip/hip_fp16.h>

#define HDIM 1024
#define BATCH 64
#define SEQ 2048
#define MTOT (BATCH*SEQ)   // 131072
#define BM 128
#define BN 256
#define BK 64
#define NKT (HDIM/BK)      // 16 k-tiles
#define NNT (HDIM/BN)      // 4 n-tiles

typedef float f32x4 __attribute__((ext_vector_type(4)));
typedef _Float16 half8 __attribute__((ext_vector_type(8)));

static __device__ __forceinline__ void gload_lds16(const void* g, void* l) {
  __builtin_amdgcn_global_load_lds((const __attribute__((address_space(1))) void*)g,
                                   (__attribute__((address_space(3))) void*)l, 16, 0, 0);
}

// ---------------- kernel 1: W1 [h][k] fp32 -> W1T [k][h] fp16 ----------------
__global__ void k_w1t(const float* __restrict__ W1, unsigned short* __restrict__ W1T) {
  __shared__ float tile[64][65];
  int h0 = blockIdx.x * 64, k0 = blockIdx.y * 64;
  int t = threadIdx.x;
#pragma unroll
  for (int j = 0; j < 4; ++j) {
    int q = j * 256 + t, r = q >> 4, c = (q & 15) * 4;
    float4 v = *(const float4*)(W1 + (size_t)(h0 + r) * HDIM + k0 + c);
    tile[r][c + 0] = v.x; tile[r][c + 1] = v.y; tile[r][c + 2] = v.z; tile[r][c + 3] = v.w;
  }
  __syncthreads();
#pragma unroll
  for (int j = 0; j < 4; ++j) {
    int q = j * 256 + t, r = q >> 4, c = (q & 15) * 4;
    union { _Float16 h[4]; ushort4 u; } cv;
    cv.h[0] = (_Float16)tile[c + 0][r];
    cv.h[1] = (_Float16)tile[c + 1][r];
    cv.h[2] = (_Float16)tile[c + 2][r];
    cv.h[3] = (_Float16)tile[c + 3][r];
    *(ushort4*)(W1T + (size_t)(k0 + r) * HDIM + h0 + c) = cv.u;
  }
}

// ---------------- kernel 2: dec_proj = dh @ W2 + b  (fp32) ----------------
__global__ void k_decproj(const float* __restrict__ dh, const float* __restrict__ W2,
                          const float* __restrict__ W2b, float* __restrict__ dp) {
  __shared__ float drow[HDIM];
  int b = blockIdx.x, t = threadIdx.x;
#pragma unroll
  for (int j = 0; j < 4; ++j) drow[j * 256 + t] = dh[(size_t)b * HDIM + j * 256 + t];
  __syncthreads();
  f32x4 acc = {0.f, 0.f, 0.f, 0.f};
#pragma unroll 16
  for (int h = 0; h < HDIM; ++h) {
    float d = drow[h];
    f32x4 w = *(const f32x4*)(W2 + (size_t)h * HDIM + t * 4);
    acc += w * d;
  }
  acc += *(const f32x4*)(W2b + t * 4);
  *(f32x4*)(dp + (size_t)b * HDIM + t * 4) = acc;
}

// ---------------- kernel 3: fused GEMM + tanh + v-dot -> score partials ----------------
// R12 (BM128 x BN256, 512thr/8 waves, verified 353-370us) + Bs DOUBLE-BUFFER:
// B(kt+1)/A(kt+1) issued BEFORE the MFMA phase and kept in flight across the
// lgkm-only barrier#2 -> their latency hides under ~1200cyc of MFMA, and
// barrier#1's vmcnt(0) drain becomes near-free (B(kt) landed a phase ago).
// NO sched_barrier anywhere (m141/R7 lesson: order-pinning defeats the
// compiler scheduler). LDS 16+64=80KB -> still 2 blocks/CU (launch_bounds
// already capped at 2) so the dbuf costs zero occupancy.
__global__ __launch_bounds__(512, 4) void k_scores(
    const float* __restrict__ E, const unsigned short* __restrict__ W1T,
    const float* __restrict__ W1b, const float* __restrict__ dp,
    const float* __restrict__ vw, float* __restrict__ spart) {
  __shared__ __align__(16) _Float16 As[BM * BK];            // 16384 B, swizzled
  __shared__ __align__(16) unsigned short Bs[2][BN * BK];   // 2 x 32768 B, swizzled
  float (*scr)[4] = (float(*)[4])As;                        // epilogue alias (post-barrier safe)

  int t = threadIdx.x;
  // XCD-aware remap: all 4 n-tiles of an m-tile adjacent on one XCD.
  int bid = blockIdx.x;                 // 0..4095
  int xcd = bid & 7;
  int q = bid >> 3;                     // 0..511
  int mt = (xcd << 7) + (q >> 2);       // 128 m-tiles per XCD
  int nt = q & 3;
  int m0 = mt * BM, n0 = nt * BN;
  int b = m0 >> 11;

  int lane = t & 63, wid = t >> 6;      // 8 waves: wr = row-half, wc = col-quarter
  int wr = wid >> 2, wc = wid & 3;
  int l15 = lane & 15, l4 = lane >> 4;

  f32x4 acc[4][4];
#pragma unroll
  for (int i = 0; i < 4; ++i)
#pragma unroll
    for (int j = 0; j < 4; ++j) acc[i][j] = {0.f, 0.f, 0.f, 0.f};

  // A staging coords: 512 thr cover 128x64 fp32 as 4 float4/thread.
  int ar = t >> 4;                       // 0..31 ; row&7 == ar&7
  int ac = (t & 15) * 4;                 // 0..60
  int aswz = (((ac >> 3) ^ (ar & 7)) << 4) + ((ac & 7) << 1);
  const float* Ab = E + (size_t)m0 * HDIM;

  // B staging coords (4 chunks of 1KB per wave, pre-swizzled source)
  int brow_in = lane >> 3;               // row&7 within 8-row chunk
  int bu = (lane & 7) ^ brow_in;

  // ---- prologue: issue B(0) -> Bs[0]; load A(0) -> regs
#pragma unroll
  for (int j = 0; j < 4; ++j) {
    int chunk = wid * 4 + j;
    int row = chunk * 8 + brow_in;
    gload_lds16(W1T + (size_t)(n0 + row) * HDIM + bu * 8, (char*)Bs[0] + (size_t)chunk * 1024);
  }
  float4 areg[4];
#pragma unroll
  for (int j = 0; j < 4; ++j)
    areg[j] = *(const float4*)(Ab + (size_t)(j * 32 + ar) * HDIM + ac);

  for (int kt = 0; kt < NKT; ++kt) {
    // (1) cvt A(kt) regs -> fp16 -> swizzled As (waits areg; leaves newer B DMA flying)
#pragma unroll
    for (int j = 0; j < 4; ++j) {
      union { _Float16 h[4]; unsigned long long u64; } cv;
      cv.h[0] = (_Float16)areg[j].x; cv.h[1] = (_Float16)areg[j].y;
      cv.h[2] = (_Float16)areg[j].z; cv.h[3] = (_Float16)areg[j].w;
      *(unsigned long long*)((char*)As + (j * 32 + ar) * 128 + aswz) = cv.u64;
    }

    // (2) barrier #1: drains B(kt) DMA (landed during prev MFMA phase -> cheap)
    //     + As writes visible to all waves.
    __syncthreads();

    // (3) issue A(kt+1) -> regs and B(kt+1) -> Bs[(kt+1)&1]; both fly through
    //     the MFMA phase below and across barrier #2.
    int ktn = ((kt + 1) & (NKT - 1)) * BK;
#pragma unroll
    for (int j = 0; j < 4; ++j)
      areg[j] = *(const float4*)(Ab + (size_t)(j * 32 + ar) * HDIM + ktn + ac);
    {
      char* bdst = (char*)Bs[(kt + 1) & 1];
#pragma unroll
      for (int j = 0; j < 4; ++j) {
        int chunk = wid * 4 + j;
        int row = chunk * 8 + brow_in;
        gload_lds16(W1T + (size_t)(n0 + row) * HDIM + ktn + bu * 8, bdst + (size_t)chunk * 1024);
      }
    }

    // (4) fragments + MFMA on As, Bs[kt&1] (swizzled reads: 0 conflicts)
    const char* Bc = (const char*)Bs[kt & 1];
    __builtin_amdgcn_s_setprio(1);
#pragma unroll
    for (int ks = 0; ks < 2; ++ks) {
      half8 af[4], bf[4];
#pragma unroll
      for (int mi = 0; mi < 4; ++mi) {
        int row = wr * 64 + mi * 16 + l15;
        af[mi] = *(const half8*)((const char*)As + row * 128 + (((ks * 4 + l4) ^ (row & 7)) << 4));
      }
#pragma unroll
      for (int ni = 0; ni < 4; ++ni) {
        int row = wc * 64 + ni * 16 + l15;
        bf[ni] = *(const half8*)(Bc + row * 128 + (((ks * 4 + l4) ^ (row & 7)) << 4));
      }
#pragma unroll
      for (int mi = 0; mi < 4; ++mi)
#pragma unroll
        for (int ni = 0; ni < 4; ++ni)
          acc[mi][ni] = __builtin_amdgcn_mfma_f32_16x16x32_f16(af[mi], bf[ni], acc[mi][ni], 0, 0, 0);
    }
    __builtin_amdgcn_s_setprio(0);

    // (5) barrier #2: LDS reads done (lgkm only) — prefetches stay in flight.
    asm volatile("s_waitcnt lgkmcnt(0)\n\ts_barrier" ::: "memory");
  }

  // epilogue: bias/v loaded here (VGPR headroom during loop)
  float bias_l[4], v_l[4];
#pragma unroll
  for (int ni = 0; ni < 4; ++ni) {
    int k = n0 + wc * 64 + ni * 16 + l15;
    bias_l[ni] = W1b[k] + dp[(size_t)b * HDIM + k];
    v_l[ni] = vw[k];
  }
#pragma unroll
  for (int mi = 0; mi < 4; ++mi) {
#pragma unroll
    for (int r = 0; r < 4; ++r) {
      float s = 0.f;
#pragma unroll
      for (int ni = 0; ni < 4; ++ni) {
        float x = acc[mi][ni][r] + bias_l[ni];
        float ex = __expf(2.f * x);
        float th = 1.f - 2.f / (ex + 1.f);
        s += th * v_l[ni];
      }
      s += __shfl_xor(s, 1); s += __shfl_xor(s, 2);
      s += __shfl_xor(s, 4); s += __shfl_xor(s, 8);
      if (l15 == 0) scr[wr * 64 + mi * 16 + l4 * 4 + r][wc] = s;
    }
  }
  __syncthreads();
  if (t < BM) {
    f32x4 p = *(const f32x4*)scr[t];
    spart[((size_t)m0 + t) * NNT + nt] = (p[0] + p[1]) + (p[2] + p[3]);
  }
}

// ---------------- kernel 4: softmax over S per batch ----------------
__global__ void k_softmax(const float* __restrict__ spart, float* __restrict__ attn) {
  __shared__ float sc[SEQ];
  __shared__ float red[8];
  int b = blockIdx.x, t = threadIdx.x;
  float mx = -1e30f;
#pragma unroll
  for (int j = 0; j < 8; ++j) {
    int s = j * 256 + t;
    f32x4 x = *(const f32x4*)(spart + ((size_t)b * SEQ + s) * NNT);
    float v = (x[0] + x[1]) + (x[2] + x[3]);
    sc[s] = v;
    mx = fmaxf(mx, v);
  }
  for (int m = 1; m < 64; m <<= 1) mx = fmaxf(mx, __shfl_xor(mx, m));
  if ((t & 63) == 0) red[t >> 6] = mx;
  __syncthreads();
  mx = fmaxf(fmaxf(red[0], red[1]), fmaxf(red[2], red[3]));
  float w[8]; float sum = 0.f;
#pragma unroll
  for (int j = 0; j < 8; ++j) {
    float e = __expf(sc[j * 256 + t] - mx);
    w[j] = e; sum += e;
  }
  for (int m = 1; m < 64; m <<= 1) sum += __shfl_xor(sum, m);
  if ((t & 63) == 0) red[4 + (t >> 6)] = sum;
  __syncthreads();
  float inv = 1.f / (red[4] + red[5] + red[6] + red[7]);
#pragma unroll
  for (int j = 0; j < 8; ++j)
    attn[(size_t)b * SEQ + j * 256 + t] = w[j] * inv;
}

// ---------------- kernel 5: context partials over s-chunks ----------------
__global__ void k_ctx_part(const float* __restrict__ E, const float* __restrict__ attn,
                           float* __restrict__ cpart, int rpc) {
  int b = blockIdx.y, ch = blockIdx.x, nch = gridDim.x;
  int t = threadIdx.x;
  const float* wrow = attn + (size_t)b * SEQ + (size_t)ch * rpc;
  const float* Eb = E + ((size_t)b * SEQ + (size_t)ch * rpc) * HDIM;
  f32x4 acc = {0.f, 0.f, 0.f, 0.f};
#pragma unroll 4
  for (int s = 0; s < rpc; ++s) {
    float w = wrow[s];
    f32x4 e = *(const f32x4*)(Eb + (size_t)s * HDIM + t * 4);
    acc += e * w;
  }
  *(f32x4*)(cpart + ((size_t)b * nch + ch) * HDIM + t * 4) = acc;
}

// ---------------- kernel 6: reduce context partials ----------------
__global__ void k_ctx_reduce(const float* __restrict__ cpart, float* __restrict__ ctx, int nch) {
  int idx = blockIdx.x * 256 + threadIdx.x;  // 0..65535
  int b = idx >> 10, k = idx & 1023;
  float s = 0.f;
  for (int c = 0; c < nch; ++c) s += cpart[((size_t)(b * nch + c)) * HDIM + k];
  ctx[idx] = s;
}

extern "C" void kernel_launch(void* const* d_in, const int* in_sizes, int n_in,
                              void* d_out, int out_size, void* d_ws, size_t ws_size,
                              hipStream_t stream) {
  const float* dh  = (const float*)d_in[0];
  const float* E   = (const float*)d_in[1];
  const float* W1w = (const float*)d_in[2];
  const float* W1b = (const float*)d_in[3];
  const float* W2w = (const float*)d_in[4];
  const float* W2b = (const float*)d_in[5];
  const float* vw  = (const float*)d_in[6];
  float* out  = (float*)d_out;
  float* ctx  = out;                 // [64,1024]
  float* attn = out + BATCH * HDIM;  // [64,2048]

  char* ws = (char*)d_ws;
  unsigned short* W1T = (unsigned short*)ws;                 // 2 MB
  float* dp    = (float*)(ws + (2u << 20));                  // 256 KB
  float* spart = (float*)(ws + (2u << 20) + (256u << 10));   // 2 MB used (4 MB reserved)
  float* cpart = (float*)(ws + (6u << 20) + (256u << 10));   // up to 8 MB

  size_t need32 = (6u << 20) + (256u << 10) + (size_t)BATCH * 32 * HDIM * 4;
  int nch = (ws_size >= need32) ? 32 : 16;
  int rpc = SEQ / nch;

  k_w1t<<<dim3(16, 16), 256, 0, stream>>>(W1w, W1T);
  k_decproj<<<BATCH, 256, 0, stream>>>(dh, W2w, W2b, dp);
  k_scores<<<(MTOT / BM) * NNT, 512, 0, stream>>>(E, W1T, W1b, dp, vw, spart);
  k_softmax<<<BATCH, 256, 0, stream>>>(spart, attn);
  k_ctx_part<<<dim3(nch, BATCH), 256, 0, stream>>>(E, attn, cpart, rpc);
  k_ctx_reduce<<<256, 256, 0, stream>>>(cpart, ctx, nch);
}

// Round 14
// 525.867 us; speedup vs baseline: 1.0534x; 1.0534x over previous
//
#include <hip/hip_runtime.h>
#include <hip/hip_bf16.h>
#include <hip/hip_fp16.h>

#define HDIM 1024
#define BATCH 64
#define SEQ 2048
#define MTOT (BATCH*SEQ)   // 131072
#define BM 128
#define BN 256
#define BK 64
#define NKT (HDIM/BK)      // 16 k-tiles
#define NNT (HDIM/BN)      // 4 n-tiles

typedef float f32x4 __attribute__((ext_vector_type(4)));
typedef _Float16 half8 __attribute__((ext_vector_type(8)));
typedef _Float16 half4v __attribute__((ext_vector_type(4)));

static __device__ __forceinline__ void gload_lds16(const void* g, void* l) {
  __builtin_amdgcn_global_load_lds((const __attribute__((address_space(1))) void*)g,
                                   (__attribute__((address_space(3))) void*)l, 16, 0, 0);
}

// ---------------- kernel 1: W1 [h][k] fp32 -> W1T [k][h] fp16 ----------------
__global__ void k_w1t(const float* __restrict__ W1, unsigned short* __restrict__ W1T) {
  __shared__ float tile[64][65];
  int h0 = blockIdx.x * 64, k0 = blockIdx.y * 64;
  int t = threadIdx.x;
#pragma unroll
  for (int j = 0; j < 4; ++j) {
    int q = j * 256 + t, r = q >> 4, c = (q & 15) * 4;
    float4 v = *(const float4*)(W1 + (size_t)(h0 + r) * HDIM + k0 + c);
    tile[r][c + 0] = v.x; tile[r][c + 1] = v.y; tile[r][c + 2] = v.z; tile[r][c + 3] = v.w;
  }
  __syncthreads();
#pragma unroll
  for (int j = 0; j < 4; ++j) {
    int q = j * 256 + t, r = q >> 4, c = (q & 15) * 4;
    union { _Float16 h[4]; ushort4 u; } cv;
    cv.h[0] = (_Float16)tile[c + 0][r];
    cv.h[1] = (_Float16)tile[c + 1][r];
    cv.h[2] = (_Float16)tile[c + 2][r];
    cv.h[3] = (_Float16)tile[c + 3][r];
    *(ushort4*)(W1T + (size_t)(k0 + r) * HDIM + h0 + c) = cv.u;
  }
}

// ---------------- kernel 2: dec_proj = dh @ W2 + b  (fp32) ----------------
__global__ void k_decproj(const float* __restrict__ dh, const float* __restrict__ W2,
                          const float* __restrict__ W2b, float* __restrict__ dp) {
  __shared__ float drow[HDIM];
  int b = blockIdx.x, t = threadIdx.x;
#pragma unroll
  for (int j = 0; j < 4; ++j) drow[j * 256 + t] = dh[(size_t)b * HDIM + j * 256 + t];
  __syncthreads();
  f32x4 acc = {0.f, 0.f, 0.f, 0.f};
#pragma unroll 16
  for (int h = 0; h < HDIM; ++h) {
    float d = drow[h];
    f32x4 w = *(const f32x4*)(W2 + (size_t)h * HDIM + t * 4);
    acc += w * d;
  }
  acc += *(const f32x4*)(W2b + t * 4);
  *(f32x4*)(dp + (size_t)b * HDIM + t * 4) = acc;
}

// ---------------- kernel 3: fused GEMM + tanh + v-dot -> score partials ----------------
// R12 VERBATIM (verified 353-370us, 764 TF; 4 pipelining attempts all lost to
// this simple 2-phase loop) + ONE addition: nt==0 blocks side-write their
// converted fp16 A-tiles to E16 (the values are already in registers from the
// LDS-staging cvt). 256MB of stores hidden inside a compute-bound kernel;
// k_ctx_part16 then reads fp16 E = half the tail's HBM traffic.
__global__ __launch_bounds__(512, 4) void k_scores(
    const float* __restrict__ E, const unsigned short* __restrict__ W1T,
    const float* __restrict__ W1b, const float* __restrict__ dp,
    const float* __restrict__ vw, float* __restrict__ spart,
    unsigned short* __restrict__ E16, int we16) {
  __shared__ __align__(16) _Float16 As[BM * BK];         // 16384 B, swizzled
  __shared__ __align__(16) unsigned short Bs[BN * BK];   // 32768 B, swizzled
  float (*scr)[4] = (float(*)[4])As;                     // epilogue alias (post-barrier safe)

  int t = threadIdx.x;
  // XCD-aware remap: all 4 n-tiles of an m-tile adjacent on one XCD.
  int bid = blockIdx.x;                 // 0..4095
  int xcd = bid & 7;
  int q = bid >> 3;                     // 0..511
  int mt = (xcd << 7) + (q >> 2);       // 128 m-tiles per XCD
  int nt = q & 3;
  int m0 = mt * BM, n0 = nt * BN;
  int b = m0 >> 11;

  int lane = t & 63, wid = t >> 6;      // 8 waves: wr = row-half, wc = col-quarter
  int wr = wid >> 2, wc = wid & 3;
  int l15 = lane & 15, l4 = lane >> 4;

  f32x4 acc[4][4];
#pragma unroll
  for (int i = 0; i < 4; ++i)
#pragma unroll
    for (int j = 0; j < 4; ++j) acc[i][j] = {0.f, 0.f, 0.f, 0.f};

  // A staging coords: 512 thr cover 128x64 fp32 as 4 float4/thread.
  int ar = t >> 4;                       // 0..31 ; row&7 == ar&7
  int ac = (t & 15) * 4;                 // 0..60
  int aswz = (((ac >> 3) ^ (ar & 7)) << 4) + ((ac & 7) << 1);
  const float* Ab = E + (size_t)m0 * HDIM;
  int wr16 = we16 && (nt == 0);          // this block writes the fp16 E mirror

  // prologue: A(0) -> regs
  float4 areg[4];
#pragma unroll
  for (int j = 0; j < 4; ++j)
    areg[j] = *(const float4*)(Ab + (size_t)(j * 32 + ar) * HDIM + ac);

  for (int kt = 0; kt < NKT; ++kt) {
    // (1) issue B(kt): 4 gload_lds per wave (32 chunks of 1KB), pre-swizzled src.
#pragma unroll
    for (int j = 0; j < 4; ++j) {
      int chunk = wid * 4 + j;                     // 0..31 (wave-uniform)
      int row = chunk * 8 + (lane >> 3);           // 0..255 ; row&7 == lane>>3
      int u = (lane & 7) ^ (lane >> 3);
      const unsigned short* g = W1T + (size_t)(n0 + row) * HDIM + kt * BK + u * 8;
      gload_lds16(g, (char*)Bs + (size_t)chunk * 1024);
    }

    // (2) cvt A(kt) regs -> fp16 -> swizzled LDS (+ optional E16 side-write)
#pragma unroll
    for (int j = 0; j < 4; ++j) {
      union { _Float16 h[4]; unsigned long long u64; } cv;
      cv.h[0] = (_Float16)areg[j].x; cv.h[1] = (_Float16)areg[j].y;
      cv.h[2] = (_Float16)areg[j].z; cv.h[3] = (_Float16)areg[j].w;
      *(unsigned long long*)((char*)As + (j * 32 + ar) * 128 + aswz) = cv.u64;
      if (wr16)
        *(unsigned long long*)(E16 + (size_t)(m0 + j * 32 + ar) * HDIM + kt * BK + ac) = cv.u64;
    }

    __syncthreads();   // drains B gloads + A ds_writes

    // (3) prefetch A(kt+1) -> regs; latency hides under MFMA below
    int ktn = ((kt + 1) & (NKT - 1)) * BK;
#pragma unroll
    for (int j = 0; j < 4; ++j)
      areg[j] = *(const float4*)(Ab + (size_t)(j * 32 + ar) * HDIM + ktn + ac);

    // (4) fragments + MFMA (swizzled reads: 0 conflicts)
    __builtin_amdgcn_s_setprio(1);
#pragma unroll
    for (int ks = 0; ks < 2; ++ks) {
      half8 af[4], bf[4];
#pragma unroll
      for (int mi = 0; mi < 4; ++mi) {
        int row = wr * 64 + mi * 16 + l15;
        af[mi] = *(const half8*)((const char*)As + row * 128 + (((ks * 4 + l4) ^ (row & 7)) << 4));
      }
#pragma unroll
      for (int ni = 0; ni < 4; ++ni) {
        int row = wc * 64 + ni * 16 + l15;
        bf[ni] = *(const half8*)((const char*)Bs + row * 128 + (((ks * 4 + l4) ^ (row & 7)) << 4));
      }
#pragma unroll
      for (int mi = 0; mi < 4; ++mi)
#pragma unroll
        for (int ni = 0; ni < 4; ++ni)
          acc[mi][ni] = __builtin_amdgcn_mfma_f32_16x16x32_f16(af[mi], bf[ni], acc[mi][ni], 0, 0, 0);
    }
    __builtin_amdgcn_s_setprio(0);

    __syncthreads();   // LDS reads done before next iter overwrites
  }

  // epilogue: bias/v loaded here (VGPR headroom during loop)
  float bias_l[4], v_l[4];
#pragma unroll
  for (int ni = 0; ni < 4; ++ni) {
    int k = n0 + wc * 64 + ni * 16 + l15;
    bias_l[ni] = W1b[k] + dp[(size_t)b * HDIM + k];
    v_l[ni] = vw[k];
  }
#pragma unroll
  for (int mi = 0; mi < 4; ++mi) {
#pragma unroll
    for (int r = 0; r < 4; ++r) {
      float s = 0.f;
#pragma unroll
      for (int ni = 0; ni < 4; ++ni) {
        float x = acc[mi][ni][r] + bias_l[ni];
        float ex = __expf(2.f * x);
        float th = 1.f - 2.f / (ex + 1.f);
        s += th * v_l[ni];
      }
      s += __shfl_xor(s, 1); s += __shfl_xor(s, 2);
      s += __shfl_xor(s, 4); s += __shfl_xor(s, 8);
      if (l15 == 0) scr[wr * 64 + mi * 16 + l4 * 4 + r][wc] = s;
    }
  }
  __syncthreads();
  if (t < BM) {
    f32x4 p = *(const f32x4*)scr[t];
    spart[((size_t)m0 + t) * NNT + nt] = (p[0] + p[1]) + (p[2] + p[3]);
  }
}

// ---------------- kernel 4: softmax over S per batch ----------------
__global__ void k_softmax(const float* __restrict__ spart, float* __restrict__ attn) {
  __shared__ float sc[SEQ];
  __shared__ float red[8];
  int b = blockIdx.x, t = threadIdx.x;
  float mx = -1e30f;
#pragma unroll
  for (int j = 0; j < 8; ++j) {
    int s = j * 256 + t;
    f32x4 x = *(const f32x4*)(spart + ((size_t)b * SEQ + s) * NNT);
    float v = (x[0] + x[1]) + (x[2] + x[3]);
    sc[s] = v;
    mx = fmaxf(mx, v);
  }
  for (int m = 1; m < 64; m <<= 1) mx = fmaxf(mx, __shfl_xor(mx, m));
  if ((t & 63) == 0) red[t >> 6] = mx;
  __syncthreads();
  mx = fmaxf(fmaxf(red[0], red[1]), fmaxf(red[2], red[3]));
  float w[8]; float sum = 0.f;
#pragma unroll
  for (int j = 0; j < 8; ++j) {
    float e = __expf(sc[j * 256 + t] - mx);
    w[j] = e; sum += e;
  }
  for (int m = 1; m < 64; m <<= 1) sum += __shfl_xor(sum, m);
  if ((t & 63) == 0) red[4 + (t >> 6)] = sum;
  __syncthreads();
  float inv = 1.f / (red[4] + red[5] + red[6] + red[7]);
#pragma unroll
  for (int j = 0; j < 8; ++j)
    attn[(size_t)b * SEQ + j * 256 + t] = w[j] * inv;
}

// ---------------- kernel 5a: context partials, fp32 E (fallback) ----------------
__global__ void k_ctx_part(const float* __restrict__ E, const float* __restrict__ attn,
                           float* __restrict__ cpart, int rpc) {
  int b = blockIdx.y, ch = blockIdx.x, nch = gridDim.x;
  int t = threadIdx.x;
  const float* wrow = attn + (size_t)b * SEQ + (size_t)ch * rpc;
  const float* Eb = E + ((size_t)b * SEQ + (size_t)ch * rpc) * HDIM;
  f32x4 acc = {0.f, 0.f, 0.f, 0.f};
#pragma unroll 4
  for (int s = 0; s < rpc; ++s) {
    float w = wrow[s];
    f32x4 e = *(const f32x4*)(Eb + (size_t)s * HDIM + t * 4);
    acc += e * w;
  }
  *(f32x4*)(cpart + ((size_t)b * nch + ch) * HDIM + t * 4) = acc;
}

// ---------------- kernel 5b: context partials, fp16 E mirror (half the bytes) ----------------
__global__ void k_ctx_part16(const unsigned short* __restrict__ E16, const float* __restrict__ attn,
                             float* __restrict__ cpart, int rpc) {
  int b = blockIdx.y, ch = blockIdx.x, nch = gridDim.x;
  int t = threadIdx.x;
  const float* wrow = attn + (size_t)b * SEQ + (size_t)ch * rpc;
  const unsigned short* Eb = E16 + ((size_t)b * SEQ + (size_t)ch * rpc) * HDIM;
  f32x4 acc = {0.f, 0.f, 0.f, 0.f};
#pragma unroll 4
  for (int s = 0; s < rpc; ++s) {
    float w = wrow[s];
    half4v e = *(const half4v*)(Eb + (size_t)s * HDIM + t * 4);
    acc[0] += w * (float)e[0];
    acc[1] += w * (float)e[1];
    acc[2] += w * (float)e[2];
    acc[3] += w * (float)e[3];
  }
  *(f32x4*)(cpart + ((size_t)b * nch + ch) * HDIM + t * 4) = acc;
}

// ---------------- kernel 6: reduce context partials ----------------
__global__ void k_ctx_reduce(const float* __restrict__ cpart, float* __restrict__ ctx, int nch) {
  int idx = blockIdx.x * 256 + threadIdx.x;  // 0..65535
  int b = idx >> 10, k = idx & 1023;
  float s = 0.f;
  for (int c = 0; c < nch; ++c) s += cpart[((size_t)(b * nch + c)) * HDIM + k];
  ctx[idx] = s;
}

extern "C" void kernel_launch(void* const* d_in, const int* in_sizes, int n_in,
                              void* d_out, int out_size, void* d_ws, size_t ws_size,
                              hipStream_t stream) {
  const float* dh  = (const float*)d_in[0];
  const float* E   = (const float*)d_in[1];
  const float* W1w = (const float*)d_in[2];
  const float* W1b = (const float*)d_in[3];
  const float* W2w = (const float*)d_in[4];
  const float* W2b = (const float*)d_in[5];
  const float* vw  = (const float*)d_in[6];
  float* out  = (float*)d_out;
  float* ctx  = out;                 // [64,1024]
  float* attn = out + BATCH * HDIM;  // [64,2048]

  char* ws = (char*)d_ws;
  unsigned short* W1T = (unsigned short*)ws;                 // 2 MB
  float* dp    = (float*)(ws + (2u << 20));                  // 256 KB
  float* spart = (float*)(ws + (2u << 20) + (256u << 10));   // 2 MB used (4 MB reserved)
  float* cpart = (float*)(ws + (6u << 20) + (256u << 10));   // up to 8 MB
  unsigned short* E16 = (unsigned short*)(ws + (14u << 20) + (256u << 10));  // 256 MB if it fits

  size_t need32  = (6u << 20) + (256u << 10) + (size_t)BATCH * 32 * HDIM * 4;
  size_t needE16 = (14u << 20) + (256u << 10) + (size_t)MTOT * HDIM * 2;
  int nch = (ws_size >= need32) ? 32 : 16;
  int rpc = SEQ / nch;
  int use16 = (ws_size >= needE16) ? 1 : 0;

  k_w1t<<<dim3(16, 16), 256, 0, stream>>>(W1w, W1T);
  k_decproj<<<BATCH, 256, 0, stream>>>(dh, W2w, W2b, dp);
  k_scores<<<(MTOT / BM) * NNT, 512, 0, stream>>>(E, W1T, W1b, dp, vw, spart,
                                                  use16 ? E16 : W1T, use16);
  k_softmax<<<BATCH, 256, 0, stream>>>(spart, attn);
  if (use16)
    k_ctx_part16<<<dim3(nch, BATCH), 256, 0, stream>>>(E16, attn, cpart, rpc);
  else
    k_ctx_part<<<dim3(nch, BATCH), 256, 0, stream>>>(E, attn, cpart, rpc);
  k_ctx_reduce<<<256, 256, 0, stream>>>(cpart, ctx, nch);
}

// Round 15
// 517.441 us; speedup vs baseline: 1.0706x; 1.0163x over previous
//
#include <hip/hip_runtime.h>
#include <hip/hip_bf16.h>
#include <hip/hip_fp16.h>

#define HDIM 1024
#define BATCH 64
#define SEQ 2048
#define MTOT (BATCH*SEQ)   // 131072
#define BM 128
#define BN 256
#define BK 64
#define NKT (HDIM/BK)      // 16 k-tiles
#define NNT (HDIM/BN)      // 4 n-tiles

typedef float f32x4 __attribute__((ext_vector_type(4)));
typedef _Float16 half8 __attribute__((ext_vector_type(8)));
typedef _Float16 half4v __attribute__((ext_vector_type(4)));

static __device__ __forceinline__ void gload_lds16(const void* g, void* l) {
  __builtin_amdgcn_global_load_lds((const __attribute__((address_space(1))) void*)g,
                                   (__attribute__((address_space(3))) void*)l, 16, 0, 0);
}

// ---------------- kernel 1: W1 [h][k] fp32 -> W1T [k][h] fp16 ----------------
__global__ void k_w1t(const float* __restrict__ W1, unsigned short* __restrict__ W1T) {
  __shared__ float tile[64][65];
  int h0 = blockIdx.x * 64, k0 = blockIdx.y * 64;
  int t = threadIdx.x;
#pragma unroll
  for (int j = 0; j < 4; ++j) {
    int q = j * 256 + t, r = q >> 4, c = (q & 15) * 4;
    float4 v = *(const float4*)(W1 + (size_t)(h0 + r) * HDIM + k0 + c);
    tile[r][c + 0] = v.x; tile[r][c + 1] = v.y; tile[r][c + 2] = v.z; tile[r][c + 3] = v.w;
  }
  __syncthreads();
#pragma unroll
  for (int j = 0; j < 4; ++j) {
    int q = j * 256 + t, r = q >> 4, c = (q & 15) * 4;
    union { _Float16 h[4]; ushort4 u; } cv;
    cv.h[0] = (_Float16)tile[c + 0][r];
    cv.h[1] = (_Float16)tile[c + 1][r];
    cv.h[2] = (_Float16)tile[c + 2][r];
    cv.h[3] = (_Float16)tile[c + 3][r];
    *(ushort4*)(W1T + (size_t)(k0 + r) * HDIM + h0 + c) = cv.u;
  }
}

// ---------------- kernel 2: dec_proj = dh @ W2 + b  (fp32) ----------------
__global__ void k_decproj(const float* __restrict__ dh, const float* __restrict__ W2,
                          const float* __restrict__ W2b, float* __restrict__ dp) {
  __shared__ float drow[HDIM];
  int b = blockIdx.x, t = threadIdx.x;
#pragma unroll
  for (int j = 0; j < 4; ++j) drow[j * 256 + t] = dh[(size_t)b * HDIM + j * 256 + t];
  __syncthreads();
  f32x4 acc = {0.f, 0.f, 0.f, 0.f};
#pragma unroll 16
  for (int h = 0; h < HDIM; ++h) {
    float d = drow[h];
    f32x4 w = *(const f32x4*)(W2 + (size_t)h * HDIM + t * 4);
    acc += w * d;
  }
  acc += *(const f32x4*)(W2b + t * 4);
  *(f32x4*)(dp + (size_t)b * HDIM + t * 4) = acc;
}

// ---------------- kernel 3: fused GEMM + tanh + v-dot -> score partials ----------------
// R12 core (verified 353-370us) + BALANCED E16 side-write: the 4 nt-sibling
// blocks of an m-tile stage the SAME A-tile, so block nt writes only its
// j==nt row-slice (1 store/thread/kt, was 4 on nt==0 only -> no straggler),
// via NONTEMPORAL stores (bypass L2 -> no eviction of the GEMM working set;
// R14 showed FETCH +113MB from the write stream).
__global__ __launch_bounds__(512, 4) void k_scores(
    const float* __restrict__ E, const unsigned short* __restrict__ W1T,
    const float* __restrict__ W1b, const float* __restrict__ dp,
    const float* __restrict__ vw, float* __restrict__ spart,
    unsigned short* __restrict__ E16, int we16) {
  __shared__ __align__(16) _Float16 As[BM * BK];         // 16384 B, swizzled
  __shared__ __align__(16) unsigned short Bs[BN * BK];   // 32768 B, swizzled
  float (*scr)[4] = (float(*)[4])As;                     // epilogue alias (post-barrier safe)

  int t = threadIdx.x;
  // XCD-aware remap: all 4 n-tiles of an m-tile adjacent on one XCD.
  int bid = blockIdx.x;                 // 0..4095
  int xcd = bid & 7;
  int q = bid >> 3;                     // 0..511
  int mt = (xcd << 7) + (q >> 2);       // 128 m-tiles per XCD
  int nt = q & 3;
  int m0 = mt * BM, n0 = nt * BN;
  int b = m0 >> 11;

  int lane = t & 63, wid = t >> 6;      // 8 waves: wr = row-half, wc = col-quarter
  int wr = wid >> 2, wc = wid & 3;
  int l15 = lane & 15, l4 = lane >> 4;

  f32x4 acc[4][4];
#pragma unroll
  for (int i = 0; i < 4; ++i)
#pragma unroll
    for (int j = 0; j < 4; ++j) acc[i][j] = {0.f, 0.f, 0.f, 0.f};

  // A staging coords: 512 thr cover 128x64 fp32 as 4 float4/thread.
  int ar = t >> 4;                       // 0..31 ; row&7 == ar&7
  int ac = (t & 15) * 4;                 // 0..60
  int aswz = (((ac >> 3) ^ (ar & 7)) << 4) + ((ac & 7) << 1);
  const float* Ab = E + (size_t)m0 * HDIM;

  // prologue: A(0) -> regs
  float4 areg[4];
#pragma unroll
  for (int j = 0; j < 4; ++j)
    areg[j] = *(const float4*)(Ab + (size_t)(j * 32 + ar) * HDIM + ac);

  for (int kt = 0; kt < NKT; ++kt) {
    // (1) issue B(kt): 4 gload_lds per wave (32 chunks of 1KB), pre-swizzled src.
#pragma unroll
    for (int j = 0; j < 4; ++j) {
      int chunk = wid * 4 + j;                     // 0..31 (wave-uniform)
      int row = chunk * 8 + (lane >> 3);           // 0..255 ; row&7 == lane>>3
      int u = (lane & 7) ^ (lane >> 3);
      const unsigned short* g = W1T + (size_t)(n0 + row) * HDIM + kt * BK + u * 8;
      gload_lds16(g, (char*)Bs + (size_t)chunk * 1024);
    }

    // (2) cvt A(kt) regs -> fp16 -> swizzled LDS; block's j==nt slice also goes
    //     to E16 (nontemporal, L2-bypassing, 1 store/thread/kt)
#pragma unroll
    for (int j = 0; j < 4; ++j) {
      union { _Float16 h[4]; unsigned long long u64; } cv;
      cv.h[0] = (_Float16)areg[j].x; cv.h[1] = (_Float16)areg[j].y;
      cv.h[2] = (_Float16)areg[j].z; cv.h[3] = (_Float16)areg[j].w;
      *(unsigned long long*)((char*)As + (j * 32 + ar) * 128 + aswz) = cv.u64;
      if (we16 && j == nt)
        __builtin_nontemporal_store(cv.u64,
            (unsigned long long*)(E16 + (size_t)(m0 + j * 32 + ar) * HDIM + kt * BK + ac));
    }

    __syncthreads();   // drains B gloads + A ds_writes (+1 store ack)

    // (3) prefetch A(kt+1) -> regs; latency hides under MFMA below
    int ktn = ((kt + 1) & (NKT - 1)) * BK;
#pragma unroll
    for (int j = 0; j < 4; ++j)
      areg[j] = *(const float4*)(Ab + (size_t)(j * 32 + ar) * HDIM + ktn + ac);

    // (4) fragments + MFMA (swizzled reads: 0 conflicts)
    __builtin_amdgcn_s_setprio(1);
#pragma unroll
    for (int ks = 0; ks < 2; ++ks) {
      half8 af[4], bf[4];
#pragma unroll
      for (int mi = 0; mi < 4; ++mi) {
        int row = wr * 64 + mi * 16 + l15;
        af[mi] = *(const half8*)((const char*)As + row * 128 + (((ks * 4 + l4) ^ (row & 7)) << 4));
      }
#pragma unroll
      for (int ni = 0; ni < 4; ++ni) {
        int row = wc * 64 + ni * 16 + l15;
        bf[ni] = *(const half8*)((const char*)Bs + row * 128 + (((ks * 4 + l4) ^ (row & 7)) << 4));
      }
#pragma unroll
      for (int mi = 0; mi < 4; ++mi)
#pragma unroll
        for (int ni = 0; ni < 4; ++ni)
          acc[mi][ni] = __builtin_amdgcn_mfma_f32_16x16x32_f16(af[mi], bf[ni], acc[mi][ni], 0, 0, 0);
    }
    __builtin_amdgcn_s_setprio(0);

    __syncthreads();   // LDS reads done before next iter overwrites
  }

  // epilogue: bias/v loaded here (VGPR headroom during loop)
  float bias_l[4], v_l[4];
#pragma unroll
  for (int ni = 0; ni < 4; ++ni) {
    int k = n0 + wc * 64 + ni * 16 + l15;
    bias_l[ni] = W1b[k] + dp[(size_t)b * HDIM + k];
    v_l[ni] = vw[k];
  }
#pragma unroll
  for (int mi = 0; mi < 4; ++mi) {
#pragma unroll
    for (int r = 0; r < 4; ++r) {
      float s = 0.f;
#pragma unroll
      for (int ni = 0; ni < 4; ++ni) {
        float x = acc[mi][ni][r] + bias_l[ni];
        float ex = __expf(2.f * x);
        float th = 1.f - 2.f / (ex + 1.f);
        s += th * v_l[ni];
      }
      s += __shfl_xor(s, 1); s += __shfl_xor(s, 2);
      s += __shfl_xor(s, 4); s += __shfl_xor(s, 8);
      if (l15 == 0) scr[wr * 64 + mi * 16 + l4 * 4 + r][wc] = s;
    }
  }
  __syncthreads();
  if (t < BM) {
    f32x4 p = *(const f32x4*)scr[t];
    spart[((size_t)m0 + t) * NNT + nt] = (p[0] + p[1]) + (p[2] + p[3]);
  }
}

// ---------------- kernel 4: softmax over S per batch ----------------
__global__ void k_softmax(const float* __restrict__ spart, float* __restrict__ attn) {
  __shared__ float sc[SEQ];
  __shared__ float red[8];
  int b = blockIdx.x, t = threadIdx.x;
  float mx = -1e30f;
#pragma unroll
  for (int j = 0; j < 8; ++j) {
    int s = j * 256 + t;
    f32x4 x = *(const f32x4*)(spart + ((size_t)b * SEQ + s) * NNT);
    float v = (x[0] + x[1]) + (x[2] + x[3]);
    sc[s] = v;
    mx = fmaxf(mx, v);
  }
  for (int m = 1; m < 64; m <<= 1) mx = fmaxf(mx, __shfl_xor(mx, m));
  if ((t & 63) == 0) red[t >> 6] = mx;
  __syncthreads();
  mx = fmaxf(fmaxf(red[0], red[1]), fmaxf(red[2], red[3]));
  float w[8]; float sum = 0.f;
#pragma unroll
  for (int j = 0; j < 8; ++j) {
    float e = __expf(sc[j * 256 + t] - mx);
    w[j] = e; sum += e;
  }
  for (int m = 1; m < 64; m <<= 1) sum += __shfl_xor(sum, m);
  if ((t & 63) == 0) red[4 + (t >> 6)] = sum;
  __syncthreads();
  float inv = 1.f / (red[4] + red[5] + red[6] + red[7]);
#pragma unroll
  for (int j = 0; j < 8; ++j)
    attn[(size_t)b * SEQ + j * 256 + t] = w[j] * inv;
}

// ---------------- kernel 5a: context partials, fp32 E (fallback) ----------------
__global__ void k_ctx_part(const float* __restrict__ E, const float* __restrict__ attn,
                           float* __restrict__ cpart, int rpc) {
  int b = blockIdx.y, ch = blockIdx.x, nch = gridDim.x;
  int t = threadIdx.x;
  const float* wrow = attn + (size_t)b * SEQ + (size_t)ch * rpc;
  const float* Eb = E + ((size_t)b * SEQ + (size_t)ch * rpc) * HDIM;
  f32x4 acc = {0.f, 0.f, 0.f, 0.f};
#pragma unroll 4
  for (int s = 0; s < rpc; ++s) {
    float w = wrow[s];
    f32x4 e = *(const f32x4*)(Eb + (size_t)s * HDIM + t * 4);
    acc += e * w;
  }
  *(f32x4*)(cpart + ((size_t)b * nch + ch) * HDIM + t * 4) = acc;
}

// ---------------- kernel 5b: context partials, fp16 E mirror (half the bytes) ----------------
__global__ void k_ctx_part16(const unsigned short* __restrict__ E16, const float* __restrict__ attn,
                             float* __restrict__ cpart, int rpc) {
  int b = blockIdx.y, ch = blockIdx.x, nch = gridDim.x;
  int t = threadIdx.x;
  const float* wrow = attn + (size_t)b * SEQ + (size_t)ch * rpc;
  const unsigned short* Eb = E16 + ((size_t)b * SEQ + (size_t)ch * rpc) * HDIM;
  f32x4 acc = {0.f, 0.f, 0.f, 0.f};
#pragma unroll 4
  for (int s = 0; s < rpc; ++s) {
    float w = wrow[s];
    half4v e = *(const half4v*)(Eb + (size_t)s * HDIM + t * 4);
    acc[0] += w * (float)e[0];
    acc[1] += w * (float)e[1];
    acc[2] += w * (float)e[2];
    acc[3] += w * (float)e[3];
  }
  *(f32x4*)(cpart + ((size_t)b * nch + ch) * HDIM + t * 4) = acc;
}

// ---------------- kernel 6: reduce context partials ----------------
__global__ void k_ctx_reduce(const float* __restrict__ cpart, float* __restrict__ ctx, int nch) {
  int idx = blockIdx.x * 256 + threadIdx.x;  // 0..65535
  int b = idx >> 10, k = idx & 1023;
  float s = 0.f;
  for (int c = 0; c < nch; ++c) s += cpart[((size_t)(b * nch + c)) * HDIM + k];
  ctx[idx] = s;
}

extern "C" void kernel_launch(void* const* d_in, const int* in_sizes, int n_in,
                              void* d_out, int out_size, void* d_ws, size_t ws_size,
                              hipStream_t stream) {
  const float* dh  = (const float*)d_in[0];
  const float* E   = (const float*)d_in[1];
  const float* W1w = (const float*)d_in[2];
  const float* W1b = (const float*)d_in[3];
  const float* W2w = (const float*)d_in[4];
  const float* W2b = (const float*)d_in[5];
  const float* vw  = (const float*)d_in[6];
  float* out  = (float*)d_out;
  float* ctx  = out;                 // [64,1024]
  float* attn = out + BATCH * HDIM;  // [64,2048]

  char* ws = (char*)d_ws;
  unsigned short* W1T = (unsigned short*)ws;                 // 2 MB
  float* dp    = (float*)(ws + (2u << 20));                  // 256 KB
  float* spart = (float*)(ws + (2u << 20) + (256u << 10));   // 2 MB used (4 MB reserved)
  float* cpart = (float*)(ws + (6u << 20) + (256u << 10));   // up to 8 MB
  unsigned short* E16 = (unsigned short*)(ws + (14u << 20) + (256u << 10));  // 256 MB if it fits

  size_t need32  = (6u << 20) + (256u << 10) + (size_t)BATCH * 32 * HDIM * 4;
  size_t needE16 = (14u << 20) + (256u << 10) + (size_t)MTOT * HDIM * 2;
  int nch = (ws_size >= need32) ? 32 : 16;
  int rpc = SEQ / nch;
  int use16 = (ws_size >= needE16) ? 1 : 0;

  k_w1t<<<dim3(16, 16), 256, 0, stream>>>(W1w, W1T);
  k_decproj<<<BATCH, 256, 0, stream>>>(dh, W2w, W2b, dp);
  k_scores<<<(MTOT / BM) * NNT, 512, 0, stream>>>(E, W1T, W1b, dp, vw, spart,
                                                  use16 ? E16 : W1T, use16);
  k_softmax<<<BATCH, 256, 0, stream>>>(spart, attn);
  if (use16)
    k_ctx_part16<<<dim3(nch, BATCH), 256, 0, stream>>>(E16, attn, cpart, rpc);
  else
    k_ctx_part<<<dim3(nch, BATCH), 256, 0, stream>>>(E, attn, cpart, rpc);
  k_ctx_reduce<<<256, 256, 0, stream>>>(cpart, ctx, nch);
}